// Round 11
// baseline (390.459 us; speedup 1.0000x reference)
//
#include <hip/hip_runtime.h>

#define T_TOK 1024
#define H_DIM 1024
#define I_DIM 4096
#define NE 8

typedef __attribute__((ext_vector_type(8))) short bf16x8;
typedef __attribute__((ext_vector_type(4))) float f32x4;

__device__ __forceinline__ f32x4 mfma16(bf16x8 a, bf16x8 b, f32x4 c) {
  return __builtin_amdgcn_mfma_f32_16x16x32_bf16(a, b, c, 0, 0, 0);
}

__device__ __forceinline__ unsigned short f2bf(float x) {
  union { float f; unsigned u; } v; v.f = x;
  unsigned r = v.u + 0x7fffu + ((v.u >> 16) & 1u);  // RNE
  return (unsigned short)(r >> 16);
}

__device__ __forceinline__ unsigned cvt_pk_bf16(float a, float b) {
  unsigned r;
  asm("v_cvt_pk_bf16_f32 %0, %1, %2" : "=v"(r) : "v"(a), "v"(b));
  return r;
}

__device__ __forceinline__ void dma16(const void* g, void* l) {
  __builtin_amdgcn_global_load_lds(
      (const __attribute__((address_space(1))) unsigned*)g,
      (__attribute__((address_space(3))) unsigned*)l, 16, 0, 0);
}

// ---------------- routing ----------------
__global__ void k_route(const float* __restrict__ gates, int* __restrict__ counts,
                        int* __restrict__ tok_idx, float* __restrict__ tok_w,
                        int* __restrict__ tok_cpy) {
  int t = blockIdx.x * blockDim.x + threadIdx.x;
  if (t >= T_TOK) return;
  float g[NE];
#pragma unroll
  for (int e = 0; e < NE; ++e) g[e] = gates[t * NE + e];
  int i1 = 0; float g1 = g[0];
#pragma unroll
  for (int e = 1; e < NE; ++e) if (g[e] > g1) { g1 = g[e]; i1 = e; }
  int i2 = -1; float g2 = -1e30f;
#pragma unroll
  for (int e = 0; e < NE; ++e) if (e != i1 && g[e] > g2) { g2 = g[e]; i2 = e; }
  float wa = 1.0f / (1.0f + expf(g2 - g1));
  float wb = 1.0f - wa;
  int s1 = atomicAdd(&counts[i1], 1);
  tok_idx[i1 * T_TOK + s1] = t; tok_w[i1 * T_TOK + s1] = wa; tok_cpy[i1 * T_TOK + s1] = 0;
  int s2 = atomicAdd(&counts[i2], 1);
  tok_idx[i2 * T_TOK + s2] = t; tok_w[i2 * T_TOK + s2] = wb; tok_cpy[i2 * T_TOK + s2] = 1;
}

// ---------------- pack ----------------
__global__ void k_pack(const float* __restrict__ hs, const int* __restrict__ counts,
                       const int* __restrict__ tok_idx, const float* __restrict__ tok_w,
                       const int* __restrict__ tok_cpy, unsigned short* __restrict__ xpack,
                       float* __restrict__ row_w, int* __restrict__ inv_row) {
  int e = blockIdx.x >> 10, slot = blockIdx.x & 1023;
  if (slot >= counts[e]) return;
  int off = 0;
#pragma unroll
  for (int i = 0; i < NE; ++i) if (i < e) off += counts[i];
  int row = off + slot;
  int tok = tok_idx[e * T_TOK + slot];
  if (threadIdx.x == 0) {
    row_w[row] = tok_w[e * T_TOK + slot];
    inv_row[tok * 2 + tok_cpy[e * T_TOK + slot]] = row;
  }
  float4 v = ((const float4*)(hs + (size_t)tok * H_DIM))[threadIdx.x];
  uint2 o; o.x = cvt_pk_bf16(v.x, v.y); o.y = cvt_pk_bf16(v.z, v.w);
  ((uint2*)(xpack + (size_t)row * H_DIM))[threadIdx.x] = o;
}

// ================= GEMM1 (+SwiGLU): m97 template =================
// 128 tok x 128 w1-rows (64 gate + 64 up interleaved per 16-row frag), BK=64.
// Both operands DMA'd to LDS, single buffer, plain __syncthreads x2 per step.
// LDS chunk-major [ch][row][16B]: DMA-linear AND conflict-free (2-way) reads.
// Grid 4096 = R4 encoding: XCD = panel&7, panel's 8 mtiles dispatch-adjacent.
__global__ __launch_bounds__(256)
void k_gemm1(const float* __restrict__ w1, const unsigned short* __restrict__ xpack,
             const int* __restrict__ counts, unsigned short* __restrict__ act) {
  int b = blockIdx.x;
  int x = b & 7, s = b >> 3;
  int mt = s & 7, pl = s >> 3;        // pl in [0,64)
  int panel = pl * 8 + x;             // [0,512)
  int e = panel >> 6, nb = panel & 63;
  int cnt = counts[e];
  int m0 = mt * 128;
  if (m0 >= cnt) return;
  int off = 0;
#pragma unroll
  for (int k = 0; k < NE; ++k) if (k < e) off += counts[k];
  int n0 = nb * 64;

  __shared__ __align__(16) unsigned char AL[16384];  // A bf16 [ch8][row128][16B]
  __shared__ __align__(16) unsigned char BL[32768];  // B fp32 [ch16][row128][16B]

  int tid = threadIdx.x, lane = tid & 63;
  int wid = tid >> 6, wm = wid & 1, wn = wid >> 1;
  int lr = lane & 15, lg = lane >> 4;

  const unsigned short* xb = xpack + (size_t)(off + m0) * H_DIM;
  const float* w1e = w1 + (size_t)e * (2 * I_DIM) * H_DIM;

  // per-thread DMA source bases (column ks*64 added at stage time)
  const unsigned short* asrc[4];
#pragma unroll
  for (int i = 0; i < 4; ++i) {
    int g = i * 256 + tid, ch = g >> 7, row = g & 127;
    int gr = (m0 + row < cnt) ? row : 0;
    asrc[i] = xb + (size_t)gr * H_DIM + ch * 8;
  }
  const float* bsrc[8];
#pragma unroll
  for (int i = 0; i < 8; ++i) {
    int g = i * 256 + tid, ch = g >> 7, row = g & 127;
    int grow = ((row >> 4) & 1) * I_DIM + n0 + (row >> 5) * 16 + (row & 15);
    bsrc[i] = w1e + (size_t)grow * H_DIM + ch * 4;
  }

  f32x4 acc[4][4];
#pragma unroll
  for (int p = 0; p < 4; ++p)
#pragma unroll
    for (int q = 0; q < 4; ++q) acc[p][q] = (f32x4){0.f, 0.f, 0.f, 0.f};

  for (int ks = 0; ks < H_DIM / 64; ++ks) {
    __syncthreads();                     // prev-step LDS reads done
    int ka = ks * 64;
#pragma unroll
    for (int i = 0; i < 4; ++i) dma16(asrc[i] + ka, AL + (i * 256 + tid) * 16);
#pragma unroll
    for (int i = 0; i < 8; ++i) dma16(bsrc[i] + ka, BL + (i * 256 + tid) * 16);
    __syncthreads();                     // compiler drains vmcnt here (m97 pattern)
#pragma unroll
    for (int kk = 0; kk < 2; ++kk) {
      bf16x8 a[4];
#pragma unroll
      for (int mr = 0; mr < 4; ++mr) {
        int r = wm * 64 + mr * 16 + lr;
        a[mr] = *(const bf16x8*)&AL[(kk * 4 + lg) * 2048 + r * 16];
      }
#pragma unroll
      for (int nr = 0; nr < 4; ++nr) {
        int r = (wn * 4 + nr) * 16 + lr;
        int ch0 = kk * 8 + lg * 2;
        f32x4 lo = *(const f32x4*)&BL[ch0 * 2048 + r * 16];
        f32x4 hi = *(const f32x4*)&BL[(ch0 + 1) * 2048 + r * 16];
        union { unsigned u[4]; bf16x8 v; } bb;
        bb.u[0] = cvt_pk_bf16(lo[0], lo[1]); bb.u[1] = cvt_pk_bf16(lo[2], lo[3]);
        bb.u[2] = cvt_pk_bf16(hi[0], hi[1]); bb.u[3] = cvt_pk_bf16(hi[2], hi[3]);
#pragma unroll
        for (int mr = 0; mr < 4; ++mr)
          acc[mr][nr] = mfma16(a[mr], bb.v, acc[mr][nr]);
      }
    }
  }

  // SwiGLU: acc[mr][2p]=gate, acc[mr][2p+1]=up; col = n0 + (wn*2+p)*16 + lr
#pragma unroll
  for (int mr = 0; mr < 4; ++mr) {
#pragma unroll
    for (int p = 0; p < 2; ++p) {
      f32x4 g = acc[mr][2 * p], u = acc[mr][2 * p + 1];
      int ncol = n0 + (wn * 2 + p) * 16 + lr;
#pragma unroll
      for (int q = 0; q < 4; ++q) {
        int rl = wm * 64 + mr * 16 + lg * 4 + q;
        if (m0 + rl < cnt) {
          float gv = g[q];
          float av = gv / (1.0f + expf(-gv)) * u[q];
          act[(size_t)(off + m0 + rl) * I_DIM + ncol] = f2bf(av);
        }
      }
    }
  }
}

// ================= GEMM2 (split-K x4): same template =================
// 128 tok x 128 h-cols, K-chunk 1024 (16 steps of 64).
// Grid 2048: vp = [e(3)][nt(3)][kc(2)]; b = ((vph*8+mt)<<3)|vpl; XCD = vp&7.
__global__ __launch_bounds__(256)
void k_gemm2(const float* __restrict__ w2, const unsigned short* __restrict__ act,
             const int* __restrict__ counts, const float* __restrict__ row_w,
             float* __restrict__ yp) {
  int b = blockIdx.x;
  int vpl = b & 7, s = b >> 3;
  int mt = s & 7, vph = s >> 3;       // vph in [0,32)
  int vp = vph * 8 + vpl;             // [0,256)
  int e = vp >> 5, nt = (vp >> 2) & 7, kc = vp & 3;
  int cnt = counts[e];
  int m0 = mt * 128;
  if (m0 >= cnt) return;
  int off = 0;
#pragma unroll
  for (int k = 0; k < NE; ++k) if (k < e) off += counts[k];
  int n0 = nt * 128;
  int kbase = kc * 1024;

  __shared__ __align__(16) unsigned char AL[16384];
  __shared__ __align__(16) unsigned char BL[32768];

  int tid = threadIdx.x, lane = tid & 63;
  int wid = tid >> 6, wm = wid & 1, wn = wid >> 1;
  int lr = lane & 15, lg = lane >> 4;

  const unsigned short* ab = act + (size_t)(off + m0) * I_DIM + kbase;
  const float* w2e = w2 + (size_t)e * H_DIM * I_DIM;

  const unsigned short* asrc[4];
#pragma unroll
  for (int i = 0; i < 4; ++i) {
    int g = i * 256 + tid, ch = g >> 7, row = g & 127;
    int gr = (m0 + row < cnt) ? row : 0;
    asrc[i] = ab + (size_t)gr * I_DIM + ch * 8;
  }
  const float* bsrc[8];
#pragma unroll
  for (int i = 0; i < 8; ++i) {
    int g = i * 256 + tid, ch = g >> 7, row = g & 127;
    bsrc[i] = w2e + (size_t)(n0 + row) * I_DIM + kbase + ch * 4;
  }

  f32x4 acc[4][4];
#pragma unroll
  for (int p = 0; p < 4; ++p)
#pragma unroll
    for (int q = 0; q < 4; ++q) acc[p][q] = (f32x4){0.f, 0.f, 0.f, 0.f};

  for (int ks = 0; ks < 16; ++ks) {
    __syncthreads();
    int ka = ks * 64;
#pragma unroll
    for (int i = 0; i < 4; ++i) dma16(asrc[i] + ka, AL + (i * 256 + tid) * 16);
#pragma unroll
    for (int i = 0; i < 8; ++i) dma16(bsrc[i] + ka, BL + (i * 256 + tid) * 16);
    __syncthreads();
#pragma unroll
    for (int kk = 0; kk < 2; ++kk) {
      bf16x8 a[4];
#pragma unroll
      for (int mr = 0; mr < 4; ++mr) {
        int r = wm * 64 + mr * 16 + lr;
        a[mr] = *(const bf16x8*)&AL[(kk * 4 + lg) * 2048 + r * 16];
      }
#pragma unroll
      for (int nr = 0; nr < 4; ++nr) {
        int r = (wn * 4 + nr) * 16 + lr;
        int ch0 = kk * 8 + lg * 2;
        f32x4 lo = *(const f32x4*)&BL[ch0 * 2048 + r * 16];
        f32x4 hi = *(const f32x4*)&BL[(ch0 + 1) * 2048 + r * 16];
        union { unsigned u[4]; bf16x8 v; } bb;
        bb.u[0] = cvt_pk_bf16(lo[0], lo[1]); bb.u[1] = cvt_pk_bf16(lo[2], lo[3]);
        bb.u[2] = cvt_pk_bf16(hi[0], hi[1]); bb.u[3] = cvt_pk_bf16(hi[2], hi[3]);
#pragma unroll
        for (int mr = 0; mr < 4; ++mr)
          acc[mr][nr] = mfma16(a[mr], bb.v, acc[mr][nr]);
      }
    }
  }

  float* ypc = yp + (size_t)kc * (2048 * H_DIM);
#pragma unroll
  for (int mr = 0; mr < 4; ++mr) {
#pragma unroll
    for (int q = 0; q < 4; ++q) {
      int rl = wm * 64 + mr * 16 + lg * 4 + q;
      if (m0 + rl >= cnt) continue;
      int grow = off + m0 + rl;
      float wgt = row_w[grow];
      float* yrow = ypc + (size_t)grow * H_DIM;
#pragma unroll
      for (int nr = 0; nr < 4; ++nr) {
        int ncol = n0 + (wn * 4 + nr) * 16 + lr;
        yrow[ncol] = acc[mr][nr][q] * wgt;
      }
    }
  }
}

// ---------------- combine ----------------
__global__ void k_combine(const float* __restrict__ yp, const int* __restrict__ inv_row,
                          float* __restrict__ out) {
  int t = blockIdx.x, i = threadIdx.x;
  int r0 = inv_row[2 * t], r1 = inv_row[2 * t + 1];
  float4 s = make_float4(0.f, 0.f, 0.f, 0.f);
#pragma unroll
  for (int kc = 0; kc < 4; ++kc) {
    const float4* a = (const float4*)(yp + (size_t)kc * (2048 * H_DIM) + (size_t)r0 * H_DIM);
    const float4* b = (const float4*)(yp + (size_t)kc * (2048 * H_DIM) + (size_t)r1 * H_DIM);
    float4 va = a[i], vb = b[i];
    s.x += va.x + vb.x; s.y += va.y + vb.y; s.z += va.z + vb.z; s.w += va.w + vb.w;
  }
  ((float4*)(out + (size_t)t * H_DIM))[i] = s;
}

extern "C" void kernel_launch(void* const* d_in, const int* in_sizes, int n_in,
                              void* d_out, int out_size, void* d_ws, size_t ws_size,
                              hipStream_t stream) {
  const float* hs = (const float*)d_in[0];
  const float* w1 = (const float*)d_in[1];
  const float* w2 = (const float*)d_in[2];
  const float* gates = (const float*)d_in[3];
  float* out = (float*)d_out;

  char* ws = (char*)d_ws;
  int* counts = (int*)ws;
  int* tok_idx = (int*)(ws + 4096);
  float* tok_w = (float*)(ws + 4096 + 32768);
  int* tok_cpy = (int*)(ws + 4096 + 65536);
  float* row_w = (float*)(ws + 4096 + 98304);
  int* inv_row = (int*)(ws + 4096 + 98304 + 8192);
  unsigned short* xpack = (unsigned short*)(ws + (1 << 17));   // 4 MB
  unsigned short* act = (unsigned short*)(ws + (8u << 20));    // 16 MB
  float* yp = (float*)(ws + (32u << 20));                      // 4 x 8 MB

  (void)hipMemsetAsync(counts, 0, NE * sizeof(int), stream);
  k_route<<<dim3(4), dim3(256), 0, stream>>>(gates, counts, tok_idx, tok_w, tok_cpy);
  k_pack<<<dim3(NE * T_TOK), dim3(256), 0, stream>>>(hs, counts, tok_idx, tok_w, tok_cpy,
                                                     xpack, row_w, inv_row);
  k_gemm1<<<dim3(4096), dim3(256), 0, stream>>>(w1, xpack, counts, act);
  k_gemm2<<<dim3(2048), dim3(256), 0, stream>>>(w2, act, counts, row_w, yp);
  k_combine<<<dim3(T_TOK), dim3(256), 0, stream>>>(yp, inv_row, out);
}